// Round 16
// baseline (376.547 us; speedup 1.0000x reference)
//
#include <hip/hip_runtime.h>
#include <hip/hip_bf16.h>
#include <math.h>

#define B_    2
#define L_    2048
#define HID_  1024
#define H_    4
#define DK_   64
#define RATIO_ 4
#define HE_   16
#define DV_   128
#define T_    64
#define NC_   32   // L_/T_
#define SPITCH 72  // bf16 LDS row pitch (scan)
#define APITCH 68  // f32 A-matrix LDS pitch (scan)
#define NCAT  1408 // concat projection width: k256 v512 g512 b16 a16 pad96

typedef __attribute__((ext_vector_type(8))) short short8;
typedef __attribute__((ext_vector_type(4))) float f32x4;

__device__ __forceinline__ float sigmoidf_(float x){ return 1.f/(1.f+expf(-x)); }
__device__ __forceinline__ ushort f2bf(float x){
  __hip_bfloat16 h = __float2bfloat16(x);
  return *reinterpret_cast<ushort*>(&h);
}
__device__ __forceinline__ float bf2f(ushort u){
  union { uint32_t i; float f; } v; v.i = ((uint32_t)u) << 16; return v.f;
}
__device__ __forceinline__ uint32_t pk2(float a, float b){
  return ((uint32_t)f2bf(b) << 16) | f2bf(a);
}
__device__ __forceinline__ void unpk8(uint4 w, float* f){
  f[0]=bf2f((ushort)(w.x&0xffff)); f[1]=bf2f((ushort)(w.x>>16));
  f[2]=bf2f((ushort)(w.y&0xffff)); f[3]=bf2f((ushort)(w.y>>16));
  f[4]=bf2f((ushort)(w.z&0xffff)); f[5]=bf2f((ushort)(w.z>>16));
  f[6]=bf2f((ushort)(w.w&0xffff)); f[7]=bf2f((ushort)(w.w>>16));
}

// ---------------- f32 -> bf16 cast ----------------
__global__ __launch_bounds__(256) void cast_bf16(const float* __restrict__ in,
                                                 ushort* __restrict__ out, int n)
{
  int i = blockIdx.x*256 + threadIdx.x;
  if (i < n) out[i] = f2bf(in[i]);
}

// ---------------- fused cast of Wq_exp / Wk_exp / Wo ----------------
__global__ __launch_bounds__(256) void cast3(const float* __restrict__ Wq_exp,
    const float* __restrict__ Wk_exp, const float* __restrict__ Wo,
    ushort* __restrict__ Wqeb, ushort* __restrict__ Wkeb, ushort* __restrict__ Wob)
{
  int i = blockIdx.x*256 + threadIdx.x;
  if      (i < 65536)  Wqeb[i]         = f2bf(Wq_exp[i]);
  else if (i < 131072) Wkeb[i-65536]   = f2bf(Wk_exp[i-65536]);
  else if (i < 655360) Wob[i-131072]   = f2bf(Wo[i-131072]);
}

// ---------------- concat weights [k|v|g|b|a|pad] -> bf16 [1408][1024] ----------------
__global__ __launch_bounds__(256) void concat_wcat(const float* __restrict__ Wk,
    const float* __restrict__ Wv, const float* __restrict__ Wg,
    const float* __restrict__ Wb, const float* __restrict__ Wa,
    ushort* __restrict__ Wcat)
{
  int idx = blockIdx.x*256 + threadIdx.x;
  if (idx >= NCAT*1024) return;
  int r = idx >> 10, cc = idx & 1023;
  float v = 0.f;
  if      (r < 256)  v = Wk[(size_t)r*1024 + cc];
  else if (r < 768)  v = Wv[(size_t)(r-256)*1024 + cc];
  else if (r < 1280) v = Wg[(size_t)(r-768)*1024 + cc];
  else if (r < 1296) v = Wb[(size_t)(r-1280)*1024 + cc];
  else if (r < 1312) v = Wa[(size_t)(r-1296)*1024 + cc];
  Wcat[idx] = f2bf(v);
}

// ---------------- bf16 MFMA GEMM (f32 out): C = A(MxK) * B(NxK)^T ----------------
__global__ __launch_bounds__(256) void gemm_bf16(
    const ushort* __restrict__ A, int lda,
    const ushort* __restrict__ Bm, int ldb,
    float* __restrict__ C, int ldc, int K)
{
  __shared__ ushort As[128*32];
  __shared__ ushort Bs[128*32];
  const int tid  = threadIdx.x;
  const int wave = tid >> 6, lane = tid & 63;
  const int row0 = blockIdx.y*128, col0 = blockIdx.x*128;
  const int wr = (wave >> 1) * 64, wc = (wave & 1) * 64;
  const int frow = lane & 15;
  const int fko  = (lane >> 4) << 3;
  f32x4 acc[4][4];
  #pragma unroll
  for (int i=0;i<4;i++)
    #pragma unroll
    for (int j=0;j<4;j++) acc[i][j] = (f32x4){0.f,0.f,0.f,0.f};
  for (int k0 = 0; k0 < K; k0 += 32) {
    #pragma unroll
    for (int cc = 0; cc < 2; cc++) {
      int c  = wave*128 + cc*64 + lane;
      int r  = c >> 2;
      int ko = (c & 3) << 3;
      __builtin_amdgcn_global_load_lds(
        (const __attribute__((address_space(1))) void*)(A + (size_t)(row0+r)*lda + k0 + ko),
        (__attribute__((address_space(3))) void*)(As + (size_t)(wave*128 + cc*64)*8),
        16, 0, 0);
      __builtin_amdgcn_global_load_lds(
        (const __attribute__((address_space(1))) void*)(Bm + (size_t)(col0+r)*ldb + k0 + ko),
        (__attribute__((address_space(3))) void*)(Bs + (size_t)(wave*128 + cc*64)*8),
        16, 0, 0);
    }
    __syncthreads();
    short8 af[4], bfv[4];
    #pragma unroll
    for (int mi=0;mi<4;mi++)
      af[mi] = *reinterpret_cast<const short8*>(&As[(wr + mi*16 + frow)*32 + fko]);
    #pragma unroll
    for (int ni=0;ni<4;ni++)
      bfv[ni] = *reinterpret_cast<const short8*>(&Bs[(wc + ni*16 + frow)*32 + fko]);
    #pragma unroll
    for (int mi=0;mi<4;mi++)
      #pragma unroll
      for (int ni=0;ni<4;ni++)
        acc[mi][ni] = __builtin_amdgcn_mfma_f32_16x16x32_bf16(af[mi], bfv[ni], acc[mi][ni], 0, 0, 0);
    __syncthreads();
  }
  const int ocol = lane & 15;
  const int orow = (lane >> 4) << 2;
  #pragma unroll
  for (int mi=0;mi<4;mi++)
    #pragma unroll
    for (int ni=0;ni<4;ni++) {
      size_t base = (size_t)(row0 + wr + mi*16 + orow)*ldc + (col0 + wc + ni*16 + ocol);
      #pragma unroll
      for (int q=0;q<4;q++) C[base + (size_t)q*ldc] = acc[mi][ni][q];
    }
}

// ---------------- bf16 MFMA GEMM (bf16 out): C = A(MxK) * B(NxK)^T ----------------
__global__ __launch_bounds__(256) void gemm_bf16_bfout(
    const ushort* __restrict__ A, int lda,
    const ushort* __restrict__ Bm, int ldb,
    ushort* __restrict__ C, int ldc, int K)
{
  __shared__ ushort As[128*32];
  __shared__ ushort Bs[128*32];
  const int tid  = threadIdx.x;
  const int wave = tid >> 6, lane = tid & 63;
  const int row0 = blockIdx.y*128, col0 = blockIdx.x*128;
  const int wr = (wave >> 1) * 64, wc = (wave & 1) * 64;
  const int frow = lane & 15;
  const int fko  = (lane >> 4) << 3;
  f32x4 acc[4][4];
  #pragma unroll
  for (int i=0;i<4;i++)
    #pragma unroll
    for (int j=0;j<4;j++) acc[i][j] = (f32x4){0.f,0.f,0.f,0.f};
  for (int k0 = 0; k0 < K; k0 += 32) {
    #pragma unroll
    for (int cc = 0; cc < 2; cc++) {
      int c  = wave*128 + cc*64 + lane;
      int r  = c >> 2;
      int ko = (c & 3) << 3;
      __builtin_amdgcn_global_load_lds(
        (const __attribute__((address_space(1))) void*)(A + (size_t)(row0+r)*lda + k0 + ko),
        (__attribute__((address_space(3))) void*)(As + (size_t)(wave*128 + cc*64)*8),
        16, 0, 0);
      __builtin_amdgcn_global_load_lds(
        (const __attribute__((address_space(1))) void*)(Bm + (size_t)(col0+r)*ldb + k0 + ko),
        (__attribute__((address_space(3))) void*)(Bs + (size_t)(wave*128 + cc*64)*8),
        16, 0, 0);
    }
    __syncthreads();
    short8 af[4], bfv[4];
    #pragma unroll
    for (int mi=0;mi<4;mi++)
      af[mi] = *reinterpret_cast<const short8*>(&As[(wr + mi*16 + frow)*32 + fko]);
    #pragma unroll
    for (int ni=0;ni<4;ni++)
      bfv[ni] = *reinterpret_cast<const short8*>(&Bs[(wc + ni*16 + frow)*32 + fko]);
    #pragma unroll
    for (int mi=0;mi<4;mi++)
      #pragma unroll
      for (int ni=0;ni<4;ni++)
        acc[mi][ni] = __builtin_amdgcn_mfma_f32_16x16x32_bf16(af[mi], bfv[ni], acc[mi][ni], 0, 0, 0);
    __syncthreads();
  }
  const int ocol = lane & 15;
  const int orow = (lane >> 4) << 2;
  #pragma unroll
  for (int mi=0;mi<4;mi++)
    #pragma unroll
    for (int ni=0;ni<4;ni++) {
      size_t base = (size_t)(row0 + wr + mi*16 + orow)*ldc + (col0 + wc + ni*16 + ocol);
      #pragma unroll
      for (int q=0;q<4;q++) C[base + (size_t)q*ldc] = f2bf(acc[mi][ni][q]);
    }
}

// ---------------- batched bf16 expansion GEMM (bf16 out), z = (q/k)*4 + h ----------------
__global__ __launch_bounds__(256) void gemm_expand_bf16(
    const ushort* __restrict__ qc_bf, const ushort* __restrict__ kc_bf,
    const ushort* __restrict__ Wqeb, const ushort* __restrict__ Wkeb,
    ushort* __restrict__ qeb, ushort* __restrict__ keb)
{
  const int z = blockIdx.z;
  const int hh = z & 3;
  const ushort* A  = (z < 4 ? qc_bf : kc_bf) + hh*64;      // lda 256
  const ushort* Bm = (z < 4 ? Wqeb  : Wkeb ) + (size_t)hh*16384; // ldb 64
  ushort* C        = (z < 4 ? qeb   : keb  ) + hh*256;     // ldc 1024
  const int lda = 256, ldb = 64, ldc = 1024, K = 64;
  __shared__ ushort As[128*32];
  __shared__ ushort Bs[128*32];
  const int tid  = threadIdx.x;
  const int wave = tid >> 6, lane = tid & 63;
  const int row0 = blockIdx.y*128, col0 = blockIdx.x*128;
  const int wr = (wave >> 1) * 64, wc = (wave & 1) * 64;
  const int frow = lane & 15;
  const int fko  = (lane >> 4) << 3;
  f32x4 acc[4][4];
  #pragma unroll
  for (int i=0;i<4;i++)
    #pragma unroll
    for (int j=0;j<4;j++) acc[i][j] = (f32x4){0.f,0.f,0.f,0.f};
  for (int k0 = 0; k0 < K; k0 += 32) {
    #pragma unroll
    for (int cc = 0; cc < 2; cc++) {
      int c  = wave*128 + cc*64 + lane;
      int r  = c >> 2;
      int ko = (c & 3) << 3;
      __builtin_amdgcn_global_load_lds(
        (const __attribute__((address_space(1))) void*)(A + (size_t)(row0+r)*lda + k0 + ko),
        (__attribute__((address_space(3))) void*)(As + (size_t)(wave*128 + cc*64)*8),
        16, 0, 0);
      __builtin_amdgcn_global_load_lds(
        (const __attribute__((address_space(1))) void*)(Bm + (size_t)(col0+r)*ldb + k0 + ko),
        (__attribute__((address_space(3))) void*)(Bs + (size_t)(wave*128 + cc*64)*8),
        16, 0, 0);
    }
    __syncthreads();
    short8 af[4], bfv[4];
    #pragma unroll
    for (int mi=0;mi<4;mi++)
      af[mi] = *reinterpret_cast<const short8*>(&As[(wr + mi*16 + frow)*32 + fko]);
    #pragma unroll
    for (int ni=0;ni<4;ni++)
      bfv[ni] = *reinterpret_cast<const short8*>(&Bs[(wc + ni*16 + frow)*32 + fko]);
    #pragma unroll
    for (int mi=0;mi<4;mi++)
      #pragma unroll
      for (int ni=0;ni<4;ni++)
        acc[mi][ni] = __builtin_amdgcn_mfma_f32_16x16x32_bf16(af[mi], bfv[ni], acc[mi][ni], 0, 0, 0);
    __syncthreads();
  }
  const int ocol = lane & 15;
  const int orow = (lane >> 4) << 2;
  #pragma unroll
  for (int mi=0;mi<4;mi++)
    #pragma unroll
    for (int ni=0;ni<4;ni++) {
      size_t base = (size_t)(row0 + wr + mi*16 + orow)*ldc + (col0 + wc + ni*16 + ocol);
      #pragma unroll
      for (int q=0;q<4;q++) C[base + (size_t)q*ldc] = f2bf(acc[mi][ni][q]);
    }
}

// ---------------- f32 GEMM with double-buffered LDS (Wq): C = A*B^T ----------------
__global__ __launch_bounds__(256) void gemm_f32_db(const float* __restrict__ A, int lda,
    const float* __restrict__ Bm, int ldb, float* __restrict__ C, int ldc,
    int M, int N, int K)
{
  __shared__ float As[2][32][64];
  __shared__ float Bs[2][32][64];
  const int tid = threadIdx.x;
  const int row0 = blockIdx.y * 64;
  const int col0 = blockIdx.x * 64;
  const int tx = tid & 15, ty = tid >> 4;
  const int r0s = tid >> 3;
  const int k4s = (tid & 7) << 2;
  float4 av0, av1, bv0, bv1;

  av0 = *(const float4*)&A[(size_t)(row0 + r0s)*lda + k4s];
  av1 = *(const float4*)&A[(size_t)(row0 + r0s + 32)*lda + k4s];
  bv0 = (col0 + r0s < N) ? *(const float4*)&Bm[(size_t)(col0 + r0s)*ldb + k4s] : make_float4(0,0,0,0);
  bv1 = (col0 + r0s + 32 < N) ? *(const float4*)&Bm[(size_t)(col0 + r0s + 32)*ldb + k4s] : make_float4(0,0,0,0);
  As[0][k4s+0][r0s] = av0.x; As[0][k4s+1][r0s] = av0.y; As[0][k4s+2][r0s] = av0.z; As[0][k4s+3][r0s] = av0.w;
  As[0][k4s+0][r0s+32] = av1.x; As[0][k4s+1][r0s+32] = av1.y; As[0][k4s+2][r0s+32] = av1.z; As[0][k4s+3][r0s+32] = av1.w;
  Bs[0][k4s+0][r0s] = bv0.x; Bs[0][k4s+1][r0s] = bv0.y; Bs[0][k4s+2][r0s] = bv0.z; Bs[0][k4s+3][r0s] = bv0.w;
  Bs[0][k4s+0][r0s+32] = bv1.x; Bs[0][k4s+1][r0s+32] = bv1.y; Bs[0][k4s+2][r0s+32] = bv1.z; Bs[0][k4s+3][r0s+32] = bv1.w;
  __syncthreads();

  float acc[4][4] = {};
  const int nt = K >> 5;
  for (int kt = 0; kt < nt; ++kt) {
    const int p = kt & 1;
    if (kt + 1 < nt) {
      int k0 = (kt+1) << 5;
      av0 = *(const float4*)&A[(size_t)(row0 + r0s)*lda + k0 + k4s];
      av1 = *(const float4*)&A[(size_t)(row0 + r0s + 32)*lda + k0 + k4s];
      bv0 = (col0 + r0s < N) ? *(const float4*)&Bm[(size_t)(col0 + r0s)*ldb + k0 + k4s] : make_float4(0,0,0,0);
      bv1 = (col0 + r0s + 32 < N) ? *(const float4*)&Bm[(size_t)(col0 + r0s + 32)*ldb + k0 + k4s] : make_float4(0,0,0,0);
    }
    #pragma unroll
    for (int kk = 0; kk < 32; kk++) {
      float4 a4 = *(const float4*)&As[p][kk][ty*4];
      float4 b4 = *(const float4*)&Bs[p][kk][tx*4];
      float a[4] = {a4.x,a4.y,a4.z,a4.w};
      float b[4] = {b4.x,b4.y,b4.z,b4.w};
      #pragma unroll
      for (int i=0;i<4;i++)
        #pragma unroll
        for (int j=0;j<4;j++) acc[i][j] += a[i]*b[j];
    }
    if (kt + 1 < nt) {
      const int q = p ^ 1;
      As[q][k4s+0][r0s] = av0.x; As[q][k4s+1][r0s] = av0.y; As[q][k4s+2][r0s] = av0.z; As[q][k4s+3][r0s] = av0.w;
      As[q][k4s+0][r0s+32] = av1.x; As[q][k4s+1][r0s+32] = av1.y; As[q][k4s+2][r0s+32] = av1.z; As[q][k4s+3][r0s+32] = av1.w;
      Bs[q][k4s+0][r0s] = bv0.x; Bs[q][k4s+1][r0s] = bv0.y; Bs[q][k4s+2][r0s] = bv0.z; Bs[q][k4s+3][r0s] = bv0.w;
      Bs[q][k4s+0][r0s+32] = bv1.x; Bs[q][k4s+1][r0s+32] = bv1.y; Bs[q][k4s+2][r0s+32] = bv1.z; Bs[q][k4s+3][r0s+32] = bv1.w;
    }
    __syncthreads();
  }
  #pragma unroll
  for (int i=0;i<4;i++) {
    int r = row0 + ty*4 + i;
    #pragma unroll
    for (int j=0;j<4;j++) {
      int cc = col0 + tx*4 + j;
      if (cc < N) C[(size_t)r*ldc + cc] = acc[i][j];
    }
  }
}

// ---------------- fused causal depthwise conv (KS=4) + SiLU for q|k|v ----------------
__global__ __launch_bounds__(256) void conv_silu_all(const float* __restrict__ q_lin,
    const ushort* __restrict__ kvgba_b, const float* __restrict__ conv_q,
    const float* __restrict__ conv_k, const float* __restrict__ conv_v,
    float* __restrict__ q_conv, ushort* __restrict__ qc_bf,
    ushort* __restrict__ kc_bf, ushort* __restrict__ v_convb)
{
  int n = blockIdx.x*256 + threadIdx.x;   // BL*1024
  int cc = n & 1023;
  int bl = n >> 10;
  int t  = bl & (L_-1);
  float acc = 0.f;
  if (cc < 256) {
    const float* w = conv_q + cc*4;
    #pragma unroll
    for (int s=0;s<4;s++){ int tt=t-3+s; if (tt>=0) acc += q_lin[(size_t)(bl-t+tt)*256 + cc]*w[s]; }
    float y = acc * sigmoidf_(acc);
    q_conv[(size_t)bl*256 + cc] = y;
    qc_bf[(size_t)bl*256 + cc] = f2bf(y);
  } else {
    int col = cc - 256;   // kvgba column (k: 0..255, v: 256..767)
    const float* w = (cc < 512) ? (conv_k + (cc-256)*4) : (conv_v + (cc-512)*4);
    #pragma unroll
    for (int s=0;s<4;s++){ int tt=t-3+s; if (tt>=0) acc += bf2f(kvgba_b[(size_t)(bl-t+tt)*NCAT + col])*w[s]; }
    float y = acc * sigmoidf_(acc);
    if (cc < 512) kc_bf[(size_t)bl*256 + (cc-256)] = f2bf(y);
    else          v_convb[(size_t)bl*512 + (cc-512)] = f2bf(y);
  }
}

// ---------------- routing + beta + g (bt/g stored TRANSPOSED [he][BL]) ----------------
__global__ __launch_bounds__(256) void routing(const float* __restrict__ qc,
    const ushort* __restrict__ kvgba_b, const float* __restrict__ Wg3,
    const float* __restrict__ A_log, const float* __restrict__ dt_bias,
    float* __restrict__ w_buf, float* __restrict__ bt_T, float* __restrict__ g_T)
{
  int n = blockIdx.x*256 + threadIdx.x;
  int h  = n & 3;
  int bl = n >> 2;
  const float* q = qc + (size_t)bl*256 + h*64;
  float l0=0.f, l1=0.f, l2=0.f;
  for (int d=0; d<64; d++) {
    float qd = q[d];
    l0 += qd*Wg3[d]; l1 += qd*Wg3[64+d]; l2 += qd*Wg3[128+d];
  }
  float mx = fmaxf(l0, fmaxf(l1, l2));
  float e0 = expf(l0-mx), e1 = expf(l1-mx), e2 = expf(l2-mx);
  float inv_s = 1.f/(e0+e1+e2);
  float p0 = e0*inv_s, p1 = e1*inv_s, p2 = e2*inv_s;
  int m1 = 0; float pm1 = p0;
  if (p1 > pm1) { m1 = 1; pm1 = p1; }
  if (p2 > pm1) { m1 = 2; pm1 = p2; }
  int ia = (m1==0) ? 1 : 0;
  int ib = (m1==2) ? 1 : 2;
  float pa = (m1==0) ? p1 : p0;
  float pb = (m1==2) ? p1 : p2;
  int   m2  = (pb > pa) ? ib : ia;
  float pm2 = (pb > pa) ? pb : pa;
  float inv_w = 1.f/(pm1 + pm2);
  float w1 = 0.5f*pm1*inv_w;
  float w2 = 0.5f*pm2*inv_w;
  #pragma unroll
  for (int r = 0; r < 4; r++) {
    float wr = (r==0) ? 0.5f : (((r-1)==m1) ? w1 : (((r-1)==m2) ? w2 : 0.f));
    int he = h*4 + r;
    w_buf[(size_t)bl*16 + he] = wr;
    float mask = (wr > 0.f) ? 1.f : 0.f;
    bt_T[(size_t)he*4096 + bl] = mask * sigmoidf_(bf2f(kvgba_b[(size_t)bl*NCAT + 1280 + he]));
    float av = bf2f(kvgba_b[(size_t)bl*NCAT + 1296 + he]) + dt_bias[he];
    float sp = fmaxf(av, 0.f) + log1pf(expf(-fabsf(av)));
    g_T[(size_t)he*4096 + bl] = -expf(A_log[he]) * sp * mask;
  }
}

// ---------------- MFMA tile helper ----------------
__device__ __forceinline__ f32x4 tile64(const ushort* Am, int r0,
                                        const ushort* Bm, int c0, int lane)
{
  f32x4 acc = {0.f,0.f,0.f,0.f};
  const int fr = lane & 15, fo = (lane >> 4) << 3;
  #pragma unroll
  for (int kk = 0; kk < 2; ++kk) {
    short8 a = *reinterpret_cast<const short8*>(&Am[(r0+fr)*SPITCH + fo + kk*32]);
    short8 b = *reinterpret_cast<const short8*>(&Bm[(c0+fr)*SPITCH + fo + kk*32]);
    acc = __builtin_amdgcn_mfma_f32_16x16x32_bf16(a, b, acc, 0, 0, 0);
  }
  return acc;
}

// ---------------- pass A via WY/UT transform + MFMA, fused l2norm ----------------
__global__ __launch_bounds__(256,2) void scan_chunk_mfma(
    const ushort* __restrict__ keb, const ushort* __restrict__ qeb,
    const ushort* __restrict__ vcb, const float* __restrict__ bt_T,
    const float* __restrict__ g_T, ushort* __restrict__ o0b,
    ushort* __restrict__ Qtb, ushort* __restrict__ Mcb, ushort* __restrict__ Bcb)
{
  __shared__ float smem[18496];                       // 73984 B
  ushort* Kbf = (ushort*)smem;
  ushort* Qbf = (ushort*)(smem + 2304);
  ushort* KTD = (ushort*)(smem + 4608);
  float*  Af  = smem + 6912;
  ushort* Pf  = (ushort*)(smem + 6912);
  ushort* UV  = (ushort*)(smem + 11264);
  float*  cgs = smem + 18176;
  float*  bts = cgs + 64;
  float*  bGs = bts + 64;
  float*  Ds  = bGs + 64;
  float*  gams= Ds + 64;

  const int id = blockIdx.x;
  const int c  = id >> 5;
  const int s  = id & 31;
  const int h  = s & 3;
  const int b  = (s >> 2) & 1;
  const int r  = s >> 3;
  const int he = h*4 + r;
  const int bhe = b*HE_ + he;
  const int tid = threadIdx.x;
  const int wave = tid >> 6, lane = tid & 63;
  const size_t l0 = (size_t)b*L_ + (size_t)c*T_;

  const int tr = tid >> 2;
  const int sg = tid & 3;
  float kf[16], qf[16];
  uint4 vw0, vw1, vw2, vw3;
  float sk, sq;
  {
    const uint4* kp = (const uint4*)(keb + (l0+tr)*1024 + he*64 + sg*16);
    const uint4* qp = (const uint4*)(qeb + (l0+tr)*1024 + he*64 + sg*16);
    uint4 kv[2] = {kp[0], kp[1]};
    uint4 qv[2] = {qp[0], qp[1]};
    unpk8(kv[0], kf); unpk8(kv[1], kf+8);
    unpk8(qv[0], qf); unpk8(qv[1], qf+8);
    float ssk = 0.f, ssq = 0.f;
    #pragma unroll
    for (int i=0;i<16;i++){ ssk += kf[i]*kf[i]; ssq += qf[i]*qf[i]; }
    ssk += __shfl_xor(ssk, 1); ssk += __shfl_xor(ssk, 2);
    ssq += __shfl_xor(ssq, 1); ssq += __shfl_xor(ssq, 2);
    sk = rsqrtf(ssk + 1e-6f);
    sq = rsqrtf(ssq + 1e-6f) * 0.125f;
    const uint4* vp = (const uint4*)(vcb + (l0+tr)*512 + h*128 + sg*32);
    vw0 = vp[0]; vw1 = vp[1]; vw2 = vp[2]; vw3 = vp[3];
  }
  if (tid < 64) {
    float g  = g_T[(size_t)he*4096 + l0 + tid];
    float bt = bt_T[(size_t)he*4096 + l0 + tid];
    float cg = g;
    #pragma unroll
    for (int off = 1; off < 64; off <<= 1) {
      float o = __shfl_up(cg, off);
      if (tid >= off) cg += o;
    }
    float cg63 = __shfl(cg, 63);
    cgs[tid] = cg; bts[tid] = bt;
    float gm = expf(cg);
    gams[tid] = gm; bGs[tid] = bt*gm; Ds[tid] = expf(cg63 - cg);
  }
  __syncthreads();
  {
    float Dt = Ds[tr];
    uint2* kdst = (uint2*)(Kbf + tr*SPITCH + sg*16);
    uint2* qdst = (uint2*)(Qbf + tr*SPITCH + sg*16);
    #pragma unroll
    for (int i=0;i<4;i++){
      kdst[i] = make_uint2(pk2(kf[4*i+0]*sk, kf[4*i+1]*sk), pk2(kf[4*i+2]*sk, kf[4*i+3]*sk));
      qdst[i] = make_uint2(pk2(qf[4*i+0]*sq, qf[4*i+1]*sq), pk2(qf[4*i+2]*sq, qf[4*i+3]*sq));
    }
    float skD = sk*Dt;
    #pragma unroll
    for (int i=0;i<16;i++){
      int d = sg*16 + i;
      KTD[d*SPITCH + tr] = f2bf(kf[i]*skD);
    }
    uint4* vdst = (uint4*)(UV + tr*128 + sg*32);
    vdst[0] = vw0; vdst[1] = vw1; vdst[2] = vw2; vdst[3] = vw3;
  }
  __syncthreads();
  // ph1: CK = K.K^T -> A
  {
    const int r0 = wave*16;
    #pragma unroll
    for (int ct=0; ct<4; ++ct) {
      f32x4 acc = tile64(Kbf, r0, Kbf, ct*16, lane);
      int t = r0 + ((lane>>4)<<2);
      int ss = ct*16 + (lane&15);
      #pragma unroll
      for (int q=0;q<4;q++){
        int tq = t + q;
        Af[tq*APITCH + ss] = (ss < tq) ? bts[tq]*expf(cgs[tq]-cgs[ss])*acc[q] : 0.f;
      }
    }
  }
  __syncthreads();
  // ph2: forward substitution
  float u[64];
  if (tid < 192) {
    if (tid < 128) {
      const ushort* Vb = UV;
      #pragma unroll
      for (int ss=0;ss<64;++ss) u[ss] = bts[ss]*bf2f(Vb[ss*128 + tid]);
    } else {
      #pragma unroll
      for (int ss=0;ss<64;++ss) u[ss] = bGs[ss]*bf2f(Kbf[ss*SPITCH + (tid-128)]);
    }
  }
  __syncthreads();
  if (tid < 192) {
    #pragma unroll
    for (int t=1;t<64;++t) {
      const float4* Ar = (const float4*)(Af + t*APITCH);
      float p0=0.f,p1=0.f,p2=0.f,p3=0.f;
      #pragma unroll
      for (int s4=0; s4*4<t; ++s4) {
        float4 a = Ar[s4];
        p0 += a.x*u[s4*4+0]; p1 += a.y*u[s4*4+1];
        p2 += a.z*u[s4*4+2]; p3 += a.w*u[s4*4+3];
      }
      u[t] -= (p0+p1)+(p2+p3);
    }
    ushort* Ut = UV;
    uint4* dst = (uint4*)&Ut[tid*SPITCH];
    #pragma unroll
    for (int i=0;i<8;++i)
      dst[i] = make_uint4(pk2(u[8*i+0],u[8*i+1]), pk2(u[8*i+2],u[8*i+3]),
                          pk2(u[8*i+4],u[8*i+5]), pk2(u[8*i+6],u[8*i+7]));
  }
  __syncthreads();
  // ph3: CQ = Q.K^T -> P
  {
    const int r0 = wave*16;
    f32x4 accs[4];
    #pragma unroll
    for (int ct=0; ct<4; ++ct) accs[ct] = tile64(Qbf, r0, Kbf, ct*16, lane);
    #pragma unroll
    for (int ct=0; ct<4; ++ct) {
      int t = r0 + ((lane>>4)<<2);
      int ss = ct*16 + (lane&15);
      #pragma unroll
      for (int q=0;q<4;q++){
        int tq = t + q;
        float val = (ss <= tq) ? expf(cgs[tq]-cgs[ss])*accs[ct][q] : 0.f;
        Pf[tq*SPITCH + ss] = f2bf(val);
      }
    }
  }
  __syncthreads();
  // ph4: output GEMMs, all outputs staged via LDS -> coalesced uint4 writes
  {
    const int r0 = wave*16;
    const int orow = (lane >> 4) << 2;
    const float gend = expf(cgs[63]);
    const ushort* Ut = UV;
    const ushort* UtK = UV + 128*SPITCH;
    const size_t bb = ((size_t)bhe*NC_ + c)*(size_t)(64*128);
    const size_t pb = ((size_t)bhe*NC_ + c)*(size_t)(64*64);
    f32x4 mv4[4], qv4[4];
    float qpre[4][4];
    #pragma unroll
    for (int ct=0; ct<4; ++ct) mv4[ct] = tile64(KTD, r0, UtK, ct*16, lane);
    #pragma unroll
    for (int ct=0; ct<4; ++ct) qv4[ct] = tile64(Pf, r0, UtK, ct*16, lane);
    #pragma unroll
    for (int ct=0; ct<4; ++ct)
      #pragma unroll
      for (int q=0;q<4;q++){
        int row = r0 + orow + q;
        int m = ct*16 + (lane&15);
        qpre[ct][q] = gams[row]*bf2f(Qbf[row*SPITCH + m]);
      }
    __syncthreads();
    ushort* MS = (ushort*)smem;
    ushort* QS = (ushort*)(smem + 2304);
    #pragma unroll
    for (int ct=0; ct<4; ++ct){
      int m = ct*16 + (lane&15);
      #pragma unroll
      for (int q=0;q<4;q++){
        int row = r0 + orow + q;
        int pc = (((m>>3)^(row&7))<<3) | (m&7);
        float val = -mv4[ct][q];
        if (row == m) val += gend;
        MS[row*64 + pc] = f2bf(val);
        QS[row*64 + pc] = f2bf(qpre[ct][q] - qv4[ct][q]);
      }
    }
    __syncthreads();
    #pragma unroll
    for (int idx = tid; idx < 512; idx += 256){
      *(uint4*)&Mcb[pb + (size_t)idx*8] = *(const uint4*)&MS[idx*8];
      *(uint4*)&Qtb[pb + (size_t)idx*8] = *(const uint4*)&QS[idx*8];
    }
    __syncthreads();
    ushort* O0s = (ushort*)smem;
    #pragma unroll
    for (int jt=0; jt<8; ++jt) {
      f32x4 acc = tile64(Pf, r0, Ut, jt*16, lane);
      int t = r0 + orow;
      int j = jt*16 + (lane&15);
      #pragma unroll
      for (int q=0;q<4;q++) O0s[(t+q)*128 + j] = f2bf(acc[q]);
    }
    __syncthreads();
    ushort* BCs = (ushort*)Af;
    #pragma unroll
    for (int jt=0; jt<8; ++jt) {
      f32x4 acc = tile64(KTD, r0, Ut, jt*16, lane);
      int i = r0 + orow;
      int j = jt*16 + (lane&15);
      #pragma unroll
      for (int q=0;q<4;q++) BCs[(i+q)*128 + j] = f2bf(acc[q]);
    }
    __syncthreads();
    #pragma unroll
    for (int idx = tid; idx < 1024; idx += 256) {
      int row = idx >> 4, seg = idx & 15;
      *(uint4*)&o0b[((l0 + row)*HE_ + he)*DV_ + seg*8] = *(const uint4*)&O0s[row*128 + seg*8];
      *(uint4*)&Bcb[bb + (size_t)row*128 + seg*8]      = *(const uint4*)&BCs[row*128 + seg*8];
    }
  }
}

// ---------------- stage one 4096-bf16 chunk (Qt or Mc) into LDS (256 thr) ----------------
__device__ __forceinline__ void stage_qm(const ushort* __restrict__ src, ushort* dst,
                                         int wave, int lane)
{
  #pragma unroll
  for (int pass = 0; pass < 2; ++pass){
    int idx = pass*256 + wave*64 + lane;   // 0..511, 16B each
    __builtin_amdgcn_global_load_lds(
      (const __attribute__((address_space(1))) void*)(src + (size_t)idx*8),
      (__attribute__((address_space(3))) void*)(dst + (size_t)idx*8), 16, 0, 0);
  }
}

// ---------------- fused pass B+C: sequential compose + correction (write-only) -----
// grid (32 s, 32 slices of 4 cols), 256-thr blocks (4 thr/row, 1 col each)
// -> 1024 blocks = 4 chains/CU (LDS 33.8KB x4 = 135KB); id%8 = s%8 -> same XCD.
// LDS read pattern identical to the proven round-11/15 shape: each read
// instruction has ALL lanes at the same gb; cluster (gb^(rw&7)) spans all 8 ->
// conflict-free. SS reads: 4 distinct words broadcast. Per-column arithmetic
// sequence identical to round 15 -> bit-identical output.
__global__ __launch_bounds__(256) void compose_correct(
    const ushort* __restrict__ Mcb, const ushort* __restrict__ Bcb,
    const ushort* __restrict__ Qtb, ushort* __restrict__ o_corrb)
{
  __shared__ ushort Ql[2][4096];  // staged Qt chunk [t][64] swizzled
  __shared__ ushort Ml[2][4096];  // staged MT chunk [i][64] swizzled
  __shared__ float SSl[256];      // running state slice [64][4]
  const int s   = blockIdx.x;
  const int h   = s & 3;
  const int b   = (s >> 2) & 1;
  const int r   = s >> 3;
  const int he  = h*4 + r;
  const int bhe = b*HE_ + he;
  const int j0  = blockIdx.y * 4;
  const int tid = threadIdx.x;
  const int wave = tid >> 6, lane = tid & 63;
  const int rw = tid >> 2;        // row 0..63
  const int jg = tid & 3;         // column within slice (1 col each)
  const int rsw = rw & 7;         // read-side granule swizzle

  for (int idx = tid; idx < 256; idx += 256) SSl[idx] = 0.f;

  stage_qm(Mcb + (size_t)(bhe*NC_)*4096, Ml[0], wave, lane);
  float bcur = bf2f(Bcb[(size_t)(bhe*NC_)*8192 + rw*128 + j0 + jg]);
  __syncthreads();

  int p = 0;
  for (int c = 0; c < NC_; ++c){
    float bnext = 0.f;
    if (c+1 < NC_){
      stage_qm(Qtb + (size_t)(bhe*NC_ + c + 1)*4096, Ql[p^1], wave, lane);
      if (c+1 < NC_-1){
        stage_qm(Mcb + (size_t)(bhe*NC_ + c + 1)*4096, Ml[p^1], wave, lane);
        bnext = bf2f(Bcb[(size_t)(bhe*NC_ + c + 1)*8192 + rw*128 + j0 + jg]);
      }
    }
    // correction term (zero at c=0) -> o_corrb (write-only, no RMW)
    float oa = 0.f;
    if (c > 0){
      const ushort* Qr = Ql[p] + rw*64;
      #pragma unroll
      for (int gb = 0; gb < 8; ++gb){
        uint4 w = *(const uint4*)&Qr[(gb ^ rsw) << 3];
        float f[8]; unpk8(w, f);
        #pragma unroll
        for (int e = 0; e < 8; ++e)
          oa += f[e]*SSl[(gb*8+e)*4 + jg];
      }
    }
    o_corrb[(((size_t)b*L_ + c*T_ + rw)*HE_ + he)*DV_ + j0 + jg] = f2bf(oa);
    // update: SS[i=rw] <- sum_m MT[rw][m]*SS[m] + B (skip at last chunk)
    float ns = bcur;
    if (c < NC_-1){
      const ushort* Mr = Ml[p] + rw*64;
      #pragma unroll
      for (int gb = 0; gb < 8; ++gb){
        uint4 w = *(const uint4*)&Mr[(gb ^ rsw) << 3];
        float f[8]; unpk8(w, f);
        #pragma unroll
        for (int e = 0; e < 8; ++e)
          ns += f[e]*SSl[(gb*8+e)*4 + jg];
      }
    }
    __syncthreads();
    if (c < NC_-1) SSl[rw*4 + jg] = ns;
    __syncthreads();     // SS visible + staged c+1 drained
    p ^= 1;
    bcur = bnext;
  }
}

// ---------------- expert combine + RMSNorm*SiLU(gate) -> bf16 ----------------
__global__ __launch_bounds__(128) void combine(const ushort* __restrict__ o0b,
    const ushort* __restrict__ o_corrb, const float* __restrict__ w_buf,
    const ushort* __restrict__ kvgba_b, const float* __restrict__ norm_w,
    ushort* __restrict__ o_fin)
{
  int n  = blockIdx.x;
  int h  = n & 3;
  int bl = n >> 2;
  int j  = threadIdx.x;
  size_t wb = (size_t)bl*16 + h*4;
  size_t ob = wb*128 + j;
  float oc = 0.f;
  #pragma unroll
  for (int r = 0; r < 4; r++){
    size_t oi = ob + (size_t)r*128;
    oc += w_buf[wb+r] * (bf2f(o0b[oi]) + bf2f(o_corrb[oi]));
  }
  float ss = oc*oc;
  #pragma unroll
  for (int off = 32; off > 0; off >>= 1) ss += __shfl_xor(ss, off);
  __shared__ float red[2];
  if ((threadIdx.x & 63) == 0) red[threadIdx.x >> 6] = ss;
  __syncthreads();
  float mean = (red[0] + red[1]) * (1.f/128.f);
  float sc = rsqrtf(mean + 1e-5f);
  float gv = bf2f(kvgba_b[(size_t)bl*NCAT + 768 + h*128 + j]);
  o_fin[(size_t)bl*512 + h*128 + j] = f2bf(oc * sc * norm_w[j] * (gv * sigmoidf_(gv)));
}

extern "C" void kernel_launch(void* const* d_in, const int* in_sizes, int n_in,
                              void* d_out, int out_size, void* d_ws, size_t ws_size,
                              hipStream_t stream)
{
  (void)in_sizes; (void)n_in; (void)out_size; (void)ws_size;
  const float* x       = (const float*)d_in[0];
  const float* Wq      = (const float*)d_in[1];
  const float* Wk      = (const float*)d_in[2];
  const float* Wv      = (const float*)d_in[3];
  const float* Wb      = (const float*)d_in[4];
  const float* Wa      = (const float*)d_in[5];
  const float* Wg      = (const float*)d_in[6];
  const float* Wo      = (const float*)d_in[7];
  const float* conv_q  = (const float*)d_in[8];
  const float* conv_k  = (const float*)d_in[9];
  const float* conv_v  = (const float*)d_in[10];
  const float* Wq_exp  = (const float*)d_in[11];
  const float* Wk_exp  = (const float*)d_in[12];
  const float* W_gate  = (const float*)d_in[13];
  const float* A_log   = (const float*)d_in[14];
  const float* dt_bias = (const float*)d_in[15];
  const float* norm_w  = (const float*)d_in[16];
  float* out = (float*)d_out;

  const size_t BL = (size_t)B_*L_;   // 4096
  float* p = (float*)d_ws;
  float* q_lin  = p; p += BL*256;
  float* q_conv = p; p += BL*256;
  float* w_buf  = p; p += BL*16;
  float* bt_T   = p; p += BL*16;   // [16][4096]
  float* g_T    = p; p += BL*16;   // [16][4096]
  ushort* kvgba_b=(ushort*)p; p += BL*NCAT/2;  // bf16 [bl][1408]
  ushort* o0b   = (ushort*)p; p += BL*16*64;   // bf16 [bl][16][128]
  ushort* o_corrb=(ushort*)p; p += BL*16*64;   // bf16 [bl][16][128]
  ushort* Mcb   = (ushort*)p; p += (size_t)B_*HE_*NC_*2048;  // bf16 [chunk][64][64]
  ushort* Qtb   = (ushort*)p; p += (size_t)B_*HE_*NC_*2048;
  ushort* Bcb   = (ushort*)p; p += (size_t)B_*HE_*NC_*4096;  // bf16 [chunk][64][128]
  ushort* v_convb=(ushort*)p; p += BL*256;        // v bf16 [bl][512]
  ushort* xb    = (ushort*)p; p += BL*512;        // x bf16
  ushort* Wcat  = (ushort*)p; p += (NCAT*1024)/2; // concat weights bf16
  ushort* qc_bf = (ushort*)p; p += BL*128;        // q_conv bf16
  ushort* kc_bf = (ushort*)p; p += BL*128;        // k_conv bf16
  ushort* qeb   = (ushort*)p; p += BL*512;        // qe bf16 [4096][1024]
  ushort* keb   = (ushort*)p; p += BL*512;        // ke bf16
  ushort* Wqeb  = (ushort*)p; p += 32768;
  ushort* Wkeb  = (ushort*)p; p += 32768;
  ushort* Wob   = (ushort*)p; p += 262144;        // 1024*512 bf16
  ushort* o_finb= (ushort*)p; p += BL*256;        // bf16 [4096][512]

  // weight prep
  concat_wcat<<<dim3((NCAT*1024+255)/256), dim3(256), 0, stream>>>(Wk, Wv, Wg, Wb, Wa, Wcat);
  { int n = (int)(BL*1024); cast_bf16<<<dim3((n+255)/256), dim3(256), 0, stream>>>(x, xb, n); }
  cast3<<<dim3((655360+255)/256), dim3(256), 0, stream>>>(Wq_exp, Wk_exp, Wo, Wqeb, Wkeb, Wob);

  // projections (kvgba bf16 out)
  gemm_f32_db<<<dim3(4, 64), dim3(256), 0, stream>>>(x, 1024, Wq, 1024, q_lin, 256, 4096, 256, 1024);
  gemm_bf16_bfout<<<dim3(NCAT/128, 32), dim3(256), 0, stream>>>(xb, 1024, Wcat, 1024, kvgba_b, NCAT, 1024);

  // fused convs (+SiLU): q|k|v in one launch
  conv_silu_all<<<dim3((int)(BL*1024/256)), dim3(256), 0, stream>>>(
      q_lin, kvgba_b, conv_q, conv_k, conv_v, q_conv, qc_bf, kc_bf, v_convb);

  routing<<<dim3(64), dim3(256), 0, stream>>>(q_conv, kvgba_b, W_gate, A_log, dt_bias,
                                              w_buf, bt_T, g_T);

  gemm_expand_bf16<<<dim3(2, 32, 8), dim3(256), 0, stream>>>(qc_bf, kc_bf, Wqeb, Wkeb, qeb, keb);

  // scan (fused l2norm): id = c*32 + s, s = r*8 + b*4 + h
  scan_chunk_mfma<<<dim3(NC_*HE_*B_), dim3(256), 0, stream>>>(keb, qeb, v_convb, bt_T, g_T,
                                                              o0b, Qtb, Mcb, Bcb);
  compose_correct<<<dim3(32, 32), dim3(256), 0, stream>>>(Mcb, Bcb, Qtb, o_corrb);
  combine<<<dim3(B_*L_*H_), dim3(128), 0, stream>>>(o0b, o_corrb, w_buf, kvgba_b, norm_w, o_finb);

  gemm_bf16<<<dim3(8, 32), dim3(256), 0, stream>>>(o_finb, 512, Wob, 512, out, 1024, 512);
}

// Round 17
// 331.808 us; speedup vs baseline: 1.1348x; 1.1348x over previous
//
#include <hip/hip_runtime.h>
#include <hip/hip_bf16.h>
#include <math.h>

#define B_    2
#define L_    2048
#define HID_  1024
#define H_    4
#define DK_   64
#define RATIO_ 4
#define HE_   16
#define DV_   128
#define T_    64
#define NC_   32   // L_/T_
#define SPITCH 72  // bf16 LDS row pitch (scan)
#define APITCH 68  // f32 A-matrix LDS pitch (scan)
#define NCAT  1408 // concat projection width: k256 v512 g512 b16 a16 pad96

typedef __attribute__((ext_vector_type(8))) short short8;
typedef __attribute__((ext_vector_type(4))) float f32x4;

__device__ __forceinline__ float sigmoidf_(float x){ return 1.f/(1.f+expf(-x)); }
__device__ __forceinline__ ushort f2bf(float x){
  __hip_bfloat16 h = __float2bfloat16(x);
  return *reinterpret_cast<ushort*>(&h);
}
__device__ __forceinline__ float bf2f(ushort u){
  union { uint32_t i; float f; } v; v.i = ((uint32_t)u) << 16; return v.f;
}
__device__ __forceinline__ uint32_t pk2(float a, float b){
  return ((uint32_t)f2bf(b) << 16) | f2bf(a);
}
__device__ __forceinline__ void unpk8(uint4 w, float* f){
  f[0]=bf2f((ushort)(w.x&0xffff)); f[1]=bf2f((ushort)(w.x>>16));
  f[2]=bf2f((ushort)(w.y&0xffff)); f[3]=bf2f((ushort)(w.y>>16));
  f[4]=bf2f((ushort)(w.z&0xffff)); f[5]=bf2f((ushort)(w.z>>16));
  f[6]=bf2f((ushort)(w.w&0xffff)); f[7]=bf2f((ushort)(w.w>>16));
}

// ---------------- f32 -> bf16 cast ----------------
__global__ __launch_bounds__(256) void cast_bf16(const float* __restrict__ in,
                                                 ushort* __restrict__ out, int n)
{
  int i = blockIdx.x*256 + threadIdx.x;
  if (i < n) out[i] = f2bf(in[i]);
}

// ---------------- fused cast of Wq_exp / Wk_exp / Wo ----------------
__global__ __launch_bounds__(256) void cast3(const float* __restrict__ Wq_exp,
    const float* __restrict__ Wk_exp, const float* __restrict__ Wo,
    ushort* __restrict__ Wqeb, ushort* __restrict__ Wkeb, ushort* __restrict__ Wob)
{
  int i = blockIdx.x*256 + threadIdx.x;
  if      (i < 65536)  Wqeb[i]         = f2bf(Wq_exp[i]);
  else if (i < 131072) Wkeb[i-65536]   = f2bf(Wk_exp[i-65536]);
  else if (i < 655360) Wob[i-131072]   = f2bf(Wo[i-131072]);
}

// ---------------- concat weights [k|v|g|b|a|pad] -> bf16 [1408][1024] ----------------
__global__ __launch_bounds__(256) void concat_wcat(const float* __restrict__ Wk,
    const float* __restrict__ Wv, const float* __restrict__ Wg,
    const float* __restrict__ Wb, const float* __restrict__ Wa,
    ushort* __restrict__ Wcat)
{
  int idx = blockIdx.x*256 + threadIdx.x;
  if (idx >= NCAT*1024) return;
  int r = idx >> 10, cc = idx & 1023;
  float v = 0.f;
  if      (r < 256)  v = Wk[(size_t)r*1024 + cc];
  else if (r < 768)  v = Wv[(size_t)(r-256)*1024 + cc];
  else if (r < 1280) v = Wg[(size_t)(r-768)*1024 + cc];
  else if (r < 1296) v = Wb[(size_t)(r-1280)*1024 + cc];
  else if (r < 1312) v = Wa[(size_t)(r-1296)*1024 + cc];
  Wcat[idx] = f2bf(v);
}

// ---------------- bf16 MFMA GEMM (f32 out): C = A(MxK) * B(NxK)^T ----------------
__global__ __launch_bounds__(256) void gemm_bf16(
    const ushort* __restrict__ A, int lda,
    const ushort* __restrict__ Bm, int ldb,
    float* __restrict__ C, int ldc, int K)
{
  __shared__ ushort As[128*32];
  __shared__ ushort Bs[128*32];
  const int tid  = threadIdx.x;
  const int wave = tid >> 6, lane = tid & 63;
  const int row0 = blockIdx.y*128, col0 = blockIdx.x*128;
  const int wr = (wave >> 1) * 64, wc = (wave & 1) * 64;
  const int frow = lane & 15;
  const int fko  = (lane >> 4) << 3;
  f32x4 acc[4][4];
  #pragma unroll
  for (int i=0;i<4;i++)
    #pragma unroll
    for (int j=0;j<4;j++) acc[i][j] = (f32x4){0.f,0.f,0.f,0.f};
  for (int k0 = 0; k0 < K; k0 += 32) {
    #pragma unroll
    for (int cc = 0; cc < 2; cc++) {
      int c  = wave*128 + cc*64 + lane;
      int r  = c >> 2;
      int ko = (c & 3) << 3;
      __builtin_amdgcn_global_load_lds(
        (const __attribute__((address_space(1))) void*)(A + (size_t)(row0+r)*lda + k0 + ko),
        (__attribute__((address_space(3))) void*)(As + (size_t)(wave*128 + cc*64)*8),
        16, 0, 0);
      __builtin_amdgcn_global_load_lds(
        (const __attribute__((address_space(1))) void*)(Bm + (size_t)(col0+r)*ldb + k0 + ko),
        (__attribute__((address_space(3))) void*)(Bs + (size_t)(wave*128 + cc*64)*8),
        16, 0, 0);
    }
    __syncthreads();
    short8 af[4], bfv[4];
    #pragma unroll
    for (int mi=0;mi<4;mi++)
      af[mi] = *reinterpret_cast<const short8*>(&As[(wr + mi*16 + frow)*32 + fko]);
    #pragma unroll
    for (int ni=0;ni<4;ni++)
      bfv[ni] = *reinterpret_cast<const short8*>(&Bs[(wc + ni*16 + frow)*32 + fko]);
    #pragma unroll
    for (int mi=0;mi<4;mi++)
      #pragma unroll
      for (int ni=0;ni<4;ni++)
        acc[mi][ni] = __builtin_amdgcn_mfma_f32_16x16x32_bf16(af[mi], bfv[ni], acc[mi][ni], 0, 0, 0);
    __syncthreads();
  }
  const int ocol = lane & 15;
  const int orow = (lane >> 4) << 2;
  #pragma unroll
  for (int mi=0;mi<4;mi++)
    #pragma unroll
    for (int ni=0;ni<4;ni++) {
      size_t base = (size_t)(row0 + wr + mi*16 + orow)*ldc + (col0 + wc + ni*16 + ocol);
      #pragma unroll
      for (int q=0;q<4;q++) C[base + (size_t)q*ldc] = acc[mi][ni][q];
    }
}

// ---------------- bf16 MFMA GEMM (bf16 out): C = A(MxK) * B(NxK)^T ----------------
__global__ __launch_bounds__(256) void gemm_bf16_bfout(
    const ushort* __restrict__ A, int lda,
    const ushort* __restrict__ Bm, int ldb,
    ushort* __restrict__ C, int ldc, int K)
{
  __shared__ ushort As[128*32];
  __shared__ ushort Bs[128*32];
  const int tid  = threadIdx.x;
  const int wave = tid >> 6, lane = tid & 63;
  const int row0 = blockIdx.y*128, col0 = blockIdx.x*128;
  const int wr = (wave >> 1) * 64, wc = (wave & 1) * 64;
  const int frow = lane & 15;
  const int fko  = (lane >> 4) << 3;
  f32x4 acc[4][4];
  #pragma unroll
  for (int i=0;i<4;i++)
    #pragma unroll
    for (int j=0;j<4;j++) acc[i][j] = (f32x4){0.f,0.f,0.f,0.f};
  for (int k0 = 0; k0 < K; k0 += 32) {
    #pragma unroll
    for (int cc = 0; cc < 2; cc++) {
      int c  = wave*128 + cc*64 + lane;
      int r  = c >> 2;
      int ko = (c & 3) << 3;
      __builtin_amdgcn_global_load_lds(
        (const __attribute__((address_space(1))) void*)(A + (size_t)(row0+r)*lda + k0 + ko),
        (__attribute__((address_space(3))) void*)(As + (size_t)(wave*128 + cc*64)*8),
        16, 0, 0);
      __builtin_amdgcn_global_load_lds(
        (const __attribute__((address_space(1))) void*)(Bm + (size_t)(col0+r)*ldb + k0 + ko),
        (__attribute__((address_space(3))) void*)(Bs + (size_t)(wave*128 + cc*64)*8),
        16, 0, 0);
    }
    __syncthreads();
    short8 af[4], bfv[4];
    #pragma unroll
    for (int mi=0;mi<4;mi++)
      af[mi] = *reinterpret_cast<const short8*>(&As[(wr + mi*16 + frow)*32 + fko]);
    #pragma unroll
    for (int ni=0;ni<4;ni++)
      bfv[ni] = *reinterpret_cast<const short8*>(&Bs[(wc + ni*16 + frow)*32 + fko]);
    #pragma unroll
    for (int mi=0;mi<4;mi++)
      #pragma unroll
      for (int ni=0;ni<4;ni++)
        acc[mi][ni] = __builtin_amdgcn_mfma_f32_16x16x32_bf16(af[mi], bfv[ni], acc[mi][ni], 0, 0, 0);
    __syncthreads();
  }
  const int ocol = lane & 15;
  const int orow = (lane >> 4) << 2;
  #pragma unroll
  for (int mi=0;mi<4;mi++)
    #pragma unroll
    for (int ni=0;ni<4;ni++) {
      size_t base = (size_t)(row0 + wr + mi*16 + orow)*ldc + (col0 + wc + ni*16 + ocol);
      #pragma unroll
      for (int q=0;q<4;q++) C[base + (size_t)q*ldc] = f2bf(acc[mi][ni][q]);
    }
}

// ---------------- batched bf16 expansion GEMM (bf16 out), z = (q/k)*4 + h ----------------
__global__ __launch_bounds__(256) void gemm_expand_bf16(
    const ushort* __restrict__ qc_bf, const ushort* __restrict__ kc_bf,
    const ushort* __restrict__ Wqeb, const ushort* __restrict__ Wkeb,
    ushort* __restrict__ qeb, ushort* __restrict__ keb)
{
  const int z = blockIdx.z;
  const int hh = z & 3;
  const ushort* A  = (z < 4 ? qc_bf : kc_bf) + hh*64;      // lda 256
  const ushort* Bm = (z < 4 ? Wqeb  : Wkeb ) + (size_t)hh*16384; // ldb 64
  ushort* C        = (z < 4 ? qeb   : keb  ) + hh*256;     // ldc 1024
  const int lda = 256, ldb = 64, ldc = 1024, K = 64;
  __shared__ ushort As[128*32];
  __shared__ ushort Bs[128*32];
  const int tid  = threadIdx.x;
  const int wave = tid >> 6, lane = tid & 63;
  const int row0 = blockIdx.y*128, col0 = blockIdx.x*128;
  const int wr = (wave >> 1) * 64, wc = (wave & 1) * 64;
  const int frow = lane & 15;
  const int fko  = (lane >> 4) << 3;
  f32x4 acc[4][4];
  #pragma unroll
  for (int i=0;i<4;i++)
    #pragma unroll
    for (int j=0;j<4;j++) acc[i][j] = (f32x4){0.f,0.f,0.f,0.f};
  for (int k0 = 0; k0 < K; k0 += 32) {
    #pragma unroll
    for (int cc = 0; cc < 2; cc++) {
      int c  = wave*128 + cc*64 + lane;
      int r  = c >> 2;
      int ko = (c & 3) << 3;
      __builtin_amdgcn_global_load_lds(
        (const __attribute__((address_space(1))) void*)(A + (size_t)(row0+r)*lda + k0 + ko),
        (__attribute__((address_space(3))) void*)(As + (size_t)(wave*128 + cc*64)*8),
        16, 0, 0);
      __builtin_amdgcn_global_load_lds(
        (const __attribute__((address_space(1))) void*)(Bm + (size_t)(col0+r)*ldb + k0 + ko),
        (__attribute__((address_space(3))) void*)(Bs + (size_t)(wave*128 + cc*64)*8),
        16, 0, 0);
    }
    __syncthreads();
    short8 af[4], bfv[4];
    #pragma unroll
    for (int mi=0;mi<4;mi++)
      af[mi] = *reinterpret_cast<const short8*>(&As[(wr + mi*16 + frow)*32 + fko]);
    #pragma unroll
    for (int ni=0;ni<4;ni++)
      bfv[ni] = *reinterpret_cast<const short8*>(&Bs[(wc + ni*16 + frow)*32 + fko]);
    #pragma unroll
    for (int mi=0;mi<4;mi++)
      #pragma unroll
      for (int ni=0;ni<4;ni++)
        acc[mi][ni] = __builtin_amdgcn_mfma_f32_16x16x32_bf16(af[mi], bfv[ni], acc[mi][ni], 0, 0, 0);
    __syncthreads();
  }
  const int ocol = lane & 15;
  const int orow = (lane >> 4) << 2;
  #pragma unroll
  for (int mi=0;mi<4;mi++)
    #pragma unroll
    for (int ni=0;ni<4;ni++) {
      size_t base = (size_t)(row0 + wr + mi*16 + orow)*ldc + (col0 + wc + ni*16 + ocol);
      #pragma unroll
      for (int q=0;q<4;q++) C[base + (size_t)q*ldc] = f2bf(acc[mi][ni][q]);
    }
}

// ---------------- f32 GEMM with double-buffered LDS (Wq): C = A*B^T ----------------
__global__ __launch_bounds__(256) void gemm_f32_db(const float* __restrict__ A, int lda,
    const float* __restrict__ Bm, int ldb, float* __restrict__ C, int ldc,
    int M, int N, int K)
{
  __shared__ float As[2][32][64];
  __shared__ float Bs[2][32][64];
  const int tid = threadIdx.x;
  const int row0 = blockIdx.y * 64;
  const int col0 = blockIdx.x * 64;
  const int tx = tid & 15, ty = tid >> 4;
  const int r0s = tid >> 3;
  const int k4s = (tid & 7) << 2;
  float4 av0, av1, bv0, bv1;

  av0 = *(const float4*)&A[(size_t)(row0 + r0s)*lda + k4s];
  av1 = *(const float4*)&A[(size_t)(row0 + r0s + 32)*lda + k4s];
  bv0 = (col0 + r0s < N) ? *(const float4*)&Bm[(size_t)(col0 + r0s)*ldb + k4s] : make_float4(0,0,0,0);
  bv1 = (col0 + r0s + 32 < N) ? *(const float4*)&Bm[(size_t)(col0 + r0s + 32)*ldb + k4s] : make_float4(0,0,0,0);
  As[0][k4s+0][r0s] = av0.x; As[0][k4s+1][r0s] = av0.y; As[0][k4s+2][r0s] = av0.z; As[0][k4s+3][r0s] = av0.w;
  As[0][k4s+0][r0s+32] = av1.x; As[0][k4s+1][r0s+32] = av1.y; As[0][k4s+2][r0s+32] = av1.z; As[0][k4s+3][r0s+32] = av1.w;
  Bs[0][k4s+0][r0s] = bv0.x; Bs[0][k4s+1][r0s] = bv0.y; Bs[0][k4s+2][r0s] = bv0.z; Bs[0][k4s+3][r0s] = bv0.w;
  Bs[0][k4s+0][r0s+32] = bv1.x; Bs[0][k4s+1][r0s+32] = bv1.y; Bs[0][k4s+2][r0s+32] = bv1.z; Bs[0][k4s+3][r0s+32] = bv1.w;
  __syncthreads();

  float acc[4][4] = {};
  const int nt = K >> 5;
  for (int kt = 0; kt < nt; ++kt) {
    const int p = kt & 1;
    if (kt + 1 < nt) {
      int k0 = (kt+1) << 5;
      av0 = *(const float4*)&A[(size_t)(row0 + r0s)*lda + k0 + k4s];
      av1 = *(const float4*)&A[(size_t)(row0 + r0s + 32)*lda + k0 + k4s];
      bv0 = (col0 + r0s < N) ? *(const float4*)&Bm[(size_t)(col0 + r0s)*ldb + k0 + k4s] : make_float4(0,0,0,0);
      bv1 = (col0 + r0s + 32 < N) ? *(const float4*)&Bm[(size_t)(col0 + r0s + 32)*ldb + k0 + k4s] : make_float4(0,0,0,0);
    }
    #pragma unroll
    for (int kk = 0; kk < 32; kk++) {
      float4 a4 = *(const float4*)&As[p][kk][ty*4];
      float4 b4 = *(const float4*)&Bs[p][kk][tx*4];
      float a[4] = {a4.x,a4.y,a4.z,a4.w};
      float b[4] = {b4.x,b4.y,b4.z,b4.w};
      #pragma unroll
      for (int i=0;i<4;i++)
        #pragma unroll
        for (int j=0;j<4;j++) acc[i][j] += a[i]*b[j];
    }
    if (kt + 1 < nt) {
      const int q = p ^ 1;
      As[q][k4s+0][r0s] = av0.x; As[q][k4s+1][r0s] = av0.y; As[q][k4s+2][r0s] = av0.z; As[q][k4s+3][r0s] = av0.w;
      As[q][k4s+0][r0s+32] = av1.x; As[q][k4s+1][r0s+32] = av1.y; As[q][k4s+2][r0s+32] = av1.z; As[q][k4s+3][r0s+32] = av1.w;
      Bs[q][k4s+0][r0s] = bv0.x; Bs[q][k4s+1][r0s] = bv0.y; Bs[q][k4s+2][r0s] = bv0.z; Bs[q][k4s+3][r0s] = bv0.w;
      Bs[q][k4s+0][r0s+32] = bv1.x; Bs[q][k4s+1][r0s+32] = bv1.y; Bs[q][k4s+2][r0s+32] = bv1.z; Bs[q][k4s+3][r0s+32] = bv1.w;
    }
    __syncthreads();
  }
  #pragma unroll
  for (int i=0;i<4;i++) {
    int r = row0 + ty*4 + i;
    #pragma unroll
    for (int j=0;j<4;j++) {
      int cc = col0 + tx*4 + j;
      if (cc < N) C[(size_t)r*ldc + cc] = acc[i][j];
    }
  }
}

// ---------------- fused causal depthwise conv (KS=4) + SiLU for q|k|v ----------------
__global__ __launch_bounds__(256) void conv_silu_all(const float* __restrict__ q_lin,
    const ushort* __restrict__ kvgba_b, const float* __restrict__ conv_q,
    const float* __restrict__ conv_k, const float* __restrict__ conv_v,
    float* __restrict__ q_conv, ushort* __restrict__ qc_bf,
    ushort* __restrict__ kc_bf, ushort* __restrict__ v_convb)
{
  int n = blockIdx.x*256 + threadIdx.x;   // BL*1024
  int cc = n & 1023;
  int bl = n >> 10;
  int t  = bl & (L_-1);
  float acc = 0.f;
  if (cc < 256) {
    const float* w = conv_q + cc*4;
    #pragma unroll
    for (int s=0;s<4;s++){ int tt=t-3+s; if (tt>=0) acc += q_lin[(size_t)(bl-t+tt)*256 + cc]*w[s]; }
    float y = acc * sigmoidf_(acc);
    q_conv[(size_t)bl*256 + cc] = y;
    qc_bf[(size_t)bl*256 + cc] = f2bf(y);
  } else {
    int col = cc - 256;   // kvgba column (k: 0..255, v: 256..767)
    const float* w = (cc < 512) ? (conv_k + (cc-256)*4) : (conv_v + (cc-512)*4);
    #pragma unroll
    for (int s=0;s<4;s++){ int tt=t-3+s; if (tt>=0) acc += bf2f(kvgba_b[(size_t)(bl-t+tt)*NCAT + col])*w[s]; }
    float y = acc * sigmoidf_(acc);
    if (cc < 512) kc_bf[(size_t)bl*256 + (cc-256)] = f2bf(y);
    else          v_convb[(size_t)bl*512 + (cc-512)] = f2bf(y);
  }
}

// ---------------- routing + beta + g (bt/g stored TRANSPOSED [he][BL]) ----------------
__global__ __launch_bounds__(256) void routing(const float* __restrict__ qc,
    const ushort* __restrict__ kvgba_b, const float* __restrict__ Wg3,
    const float* __restrict__ A_log, const float* __restrict__ dt_bias,
    float* __restrict__ w_buf, float* __restrict__ bt_T, float* __restrict__ g_T)
{
  int n = blockIdx.x*256 + threadIdx.x;
  int h  = n & 3;
  int bl = n >> 2;
  const float* q = qc + (size_t)bl*256 + h*64;
  float l0=0.f, l1=0.f, l2=0.f;
  for (int d=0; d<64; d++) {
    float qd = q[d];
    l0 += qd*Wg3[d]; l1 += qd*Wg3[64+d]; l2 += qd*Wg3[128+d];
  }
  float mx = fmaxf(l0, fmaxf(l1, l2));
  float e0 = expf(l0-mx), e1 = expf(l1-mx), e2 = expf(l2-mx);
  float inv_s = 1.f/(e0+e1+e2);
  float p0 = e0*inv_s, p1 = e1*inv_s, p2 = e2*inv_s;
  int m1 = 0; float pm1 = p0;
  if (p1 > pm1) { m1 = 1; pm1 = p1; }
  if (p2 > pm1) { m1 = 2; pm1 = p2; }
  int ia = (m1==0) ? 1 : 0;
  int ib = (m1==2) ? 1 : 2;
  float pa = (m1==0) ? p1 : p0;
  float pb = (m1==2) ? p1 : p2;
  int   m2  = (pb > pa) ? ib : ia;
  float pm2 = (pb > pa) ? pb : pa;
  float inv_w = 1.f/(pm1 + pm2);
  float w1 = 0.5f*pm1*inv_w;
  float w2 = 0.5f*pm2*inv_w;
  #pragma unroll
  for (int r = 0; r < 4; r++) {
    float wr = (r==0) ? 0.5f : (((r-1)==m1) ? w1 : (((r-1)==m2) ? w2 : 0.f));
    int he = h*4 + r;
    w_buf[(size_t)bl*16 + he] = wr;
    float mask = (wr > 0.f) ? 1.f : 0.f;
    bt_T[(size_t)he*4096 + bl] = mask * sigmoidf_(bf2f(kvgba_b[(size_t)bl*NCAT + 1280 + he]));
    float av = bf2f(kvgba_b[(size_t)bl*NCAT + 1296 + he]) + dt_bias[he];
    float sp = fmaxf(av, 0.f) + log1pf(expf(-fabsf(av)));
    g_T[(size_t)he*4096 + bl] = -expf(A_log[he]) * sp * mask;
  }
}

// ---------------- MFMA tile helper ----------------
__device__ __forceinline__ f32x4 tile64(const ushort* Am, int r0,
                                        const ushort* Bm, int c0, int lane)
{
  f32x4 acc = {0.f,0.f,0.f,0.f};
  const int fr = lane & 15, fo = (lane >> 4) << 3;
  #pragma unroll
  for (int kk = 0; kk < 2; ++kk) {
    short8 a = *reinterpret_cast<const short8*>(&Am[(r0+fr)*SPITCH + fo + kk*32]);
    short8 b = *reinterpret_cast<const short8*>(&Bm[(c0+fr)*SPITCH + fo + kk*32]);
    acc = __builtin_amdgcn_mfma_f32_16x16x32_bf16(a, b, acc, 0, 0, 0);
  }
  return acc;
}

// ---------------- pass A via WY/UT transform + MFMA, fused l2norm ----------------
__global__ __launch_bounds__(256,2) void scan_chunk_mfma(
    const ushort* __restrict__ keb, const ushort* __restrict__ qeb,
    const ushort* __restrict__ vcb, const float* __restrict__ bt_T,
    const float* __restrict__ g_T, ushort* __restrict__ o0b,
    ushort* __restrict__ Qtb, ushort* __restrict__ Mcb, ushort* __restrict__ Bcb)
{
  __shared__ float smem[18496];                       // 73984 B
  ushort* Kbf = (ushort*)smem;
  ushort* Qbf = (ushort*)(smem + 2304);
  ushort* KTD = (ushort*)(smem + 4608);
  float*  Af  = smem + 6912;
  ushort* Pf  = (ushort*)(smem + 6912);
  ushort* UV  = (ushort*)(smem + 11264);
  float*  cgs = smem + 18176;
  float*  bts = cgs + 64;
  float*  bGs = bts + 64;
  float*  Ds  = bGs + 64;
  float*  gams= Ds + 64;

  const int id = blockIdx.x;
  const int c  = id >> 5;
  const int s  = id & 31;
  const int h  = s & 3;
  const int b  = (s >> 2) & 1;
  const int r  = s >> 3;
  const int he = h*4 + r;
  const int bhe = b*HE_ + he;
  const int tid = threadIdx.x;
  const int wave = tid >> 6, lane = tid & 63;
  const size_t l0 = (size_t)b*L_ + (size_t)c*T_;

  const int tr = tid >> 2;
  const int sg = tid & 3;
  float kf[16], qf[16];
  uint4 vw0, vw1, vw2, vw3;
  float sk, sq;
  {
    const uint4* kp = (const uint4*)(keb + (l0+tr)*1024 + he*64 + sg*16);
    const uint4* qp = (const uint4*)(qeb + (l0+tr)*1024 + he*64 + sg*16);
    uint4 kv[2] = {kp[0], kp[1]};
    uint4 qv[2] = {qp[0], qp[1]};
    unpk8(kv[0], kf); unpk8(kv[1], kf+8);
    unpk8(qv[0], qf); unpk8(qv[1], qf+8);
    float ssk = 0.f, ssq = 0.f;
    #pragma unroll
    for (int i=0;i<16;i++){ ssk += kf[i]*kf[i]; ssq += qf[i]*qf[i]; }
    ssk += __shfl_xor(ssk, 1); ssk += __shfl_xor(ssk, 2);
    ssq += __shfl_xor(ssq, 1); ssq += __shfl_xor(ssq, 2);
    sk = rsqrtf(ssk + 1e-6f);
    sq = rsqrtf(ssq + 1e-6f) * 0.125f;
    const uint4* vp = (const uint4*)(vcb + (l0+tr)*512 + h*128 + sg*32);
    vw0 = vp[0]; vw1 = vp[1]; vw2 = vp[2]; vw3 = vp[3];
  }
  if (tid < 64) {
    float g  = g_T[(size_t)he*4096 + l0 + tid];
    float bt = bt_T[(size_t)he*4096 + l0 + tid];
    float cg = g;
    #pragma unroll
    for (int off = 1; off < 64; off <<= 1) {
      float o = __shfl_up(cg, off);
      if (tid >= off) cg += o;
    }
    float cg63 = __shfl(cg, 63);
    cgs[tid] = cg; bts[tid] = bt;
    float gm = expf(cg);
    gams[tid] = gm; bGs[tid] = bt*gm; Ds[tid] = expf(cg63 - cg);
  }
  __syncthreads();
  {
    float Dt = Ds[tr];
    uint2* kdst = (uint2*)(Kbf + tr*SPITCH + sg*16);
    uint2* qdst = (uint2*)(Qbf + tr*SPITCH + sg*16);
    #pragma unroll
    for (int i=0;i<4;i++){
      kdst[i] = make_uint2(pk2(kf[4*i+0]*sk, kf[4*i+1]*sk), pk2(kf[4*i+2]*sk, kf[4*i+3]*sk));
      qdst[i] = make_uint2(pk2(qf[4*i+0]*sq, qf[4*i+1]*sq), pk2(qf[4*i+2]*sq, qf[4*i+3]*sq));
    }
    float skD = sk*Dt;
    #pragma unroll
    for (int i=0;i<16;i++){
      int d = sg*16 + i;
      KTD[d*SPITCH + tr] = f2bf(kf[i]*skD);
    }
    uint4* vdst = (uint4*)(UV + tr*128 + sg*32);
    vdst[0] = vw0; vdst[1] = vw1; vdst[2] = vw2; vdst[3] = vw3;
  }
  __syncthreads();
  // ph1: CK = K.K^T -> A
  {
    const int r0 = wave*16;
    #pragma unroll
    for (int ct=0; ct<4; ++ct) {
      f32x4 acc = tile64(Kbf, r0, Kbf, ct*16, lane);
      int t = r0 + ((lane>>4)<<2);
      int ss = ct*16 + (lane&15);
      #pragma unroll
      for (int q=0;q<4;q++){
        int tq = t + q;
        Af[tq*APITCH + ss] = (ss < tq) ? bts[tq]*expf(cgs[tq]-cgs[ss])*acc[q] : 0.f;
      }
    }
  }
  __syncthreads();
  // ph2: forward substitution
  float u[64];
  if (tid < 192) {
    if (tid < 128) {
      const ushort* Vb = UV;
      #pragma unroll
      for (int ss=0;ss<64;++ss) u[ss] = bts[ss]*bf2f(Vb[ss*128 + tid]);
    } else {
      #pragma unroll
      for (int ss=0;ss<64;++ss) u[ss] = bGs[ss]*bf2f(Kbf[ss*SPITCH + (tid-128)]);
    }
  }
  __syncthreads();
  if (tid < 192) {
    #pragma unroll
    for (int t=1;t<64;++t) {
      const float4* Ar = (const float4*)(Af + t*APITCH);
      float p0=0.f,p1=0.f,p2=0.f,p3=0.f;
      #pragma unroll
      for (int s4=0; s4*4<t; ++s4) {
        float4 a = Ar[s4];
        p0 += a.x*u[s4*4+0]; p1 += a.y*u[s4*4+1];
        p2 += a.z*u[s4*4+2]; p3 += a.w*u[s4*4+3];
      }
      u[t] -= (p0+p1)+(p2+p3);
    }
    ushort* Ut = UV;
    uint4* dst = (uint4*)&Ut[tid*SPITCH];
    #pragma unroll
    for (int i=0;i<8;++i)
      dst[i] = make_uint4(pk2(u[8*i+0],u[8*i+1]), pk2(u[8*i+2],u[8*i+3]),
                          pk2(u[8*i+4],u[8*i+5]), pk2(u[8*i+6],u[8*i+7]));
  }
  __syncthreads();
  // ph3: CQ = Q.K^T -> P
  {
    const int r0 = wave*16;
    f32x4 accs[4];
    #pragma unroll
    for (int ct=0; ct<4; ++ct) accs[ct] = tile64(Qbf, r0, Kbf, ct*16, lane);
    #pragma unroll
    for (int ct=0; ct<4; ++ct) {
      int t = r0 + ((lane>>4)<<2);
      int ss = ct*16 + (lane&15);
      #pragma unroll
      for (int q=0;q<4;q++){
        int tq = t + q;
        float val = (ss <= tq) ? expf(cgs[tq]-cgs[ss])*accs[ct][q] : 0.f;
        Pf[tq*SPITCH + ss] = f2bf(val);
      }
    }
  }
  __syncthreads();
  // ph4: output GEMMs, all outputs staged via LDS -> coalesced uint4 writes
  {
    const int r0 = wave*16;
    const int orow = (lane >> 4) << 2;
    const float gend = expf(cgs[63]);
    const ushort* Ut = UV;
    const ushort* UtK = UV + 128*SPITCH;
    const size_t bb = ((size_t)bhe*NC_ + c)*(size_t)(64*128);
    const size_t pb = ((size_t)bhe*NC_ + c)*(size_t)(64*64);
    f32x4 mv4[4], qv4[4];
    float qpre[4][4];
    #pragma unroll
    for (int ct=0; ct<4; ++ct) mv4[ct] = tile64(KTD, r0, UtK, ct*16, lane);
    #pragma unroll
    for (int ct=0; ct<4; ++ct) qv4[ct] = tile64(Pf, r0, UtK, ct*16, lane);
    #pragma unroll
    for (int ct=0; ct<4; ++ct)
      #pragma unroll
      for (int q=0;q<4;q++){
        int row = r0 + orow + q;
        int m = ct*16 + (lane&15);
        qpre[ct][q] = gams[row]*bf2f(Qbf[row*SPITCH + m]);
      }
    __syncthreads();
    ushort* MS = (ushort*)smem;
    ushort* QS = (ushort*)(smem + 2304);
    #pragma unroll
    for (int ct=0; ct<4; ++ct){
      int m = ct*16 + (lane&15);
      #pragma unroll
      for (int q=0;q<4;q++){
        int row = r0 + orow + q;
        int pc = (((m>>3)^(row&7))<<3) | (m&7);
        float val = -mv4[ct][q];
        if (row == m) val += gend;
        MS[row*64 + pc] = f2bf(val);
        QS[row*64 + pc] = f2bf(qpre[ct][q] - qv4[ct][q]);
      }
    }
    __syncthreads();
    #pragma unroll
    for (int idx = tid; idx < 512; idx += 256){
      *(uint4*)&Mcb[pb + (size_t)idx*8] = *(const uint4*)&MS[idx*8];
      *(uint4*)&Qtb[pb + (size_t)idx*8] = *(const uint4*)&QS[idx*8];
    }
    __syncthreads();
    ushort* O0s = (ushort*)smem;
    #pragma unroll
    for (int jt=0; jt<8; ++jt) {
      f32x4 acc = tile64(Pf, r0, Ut, jt*16, lane);
      int t = r0 + orow;
      int j = jt*16 + (lane&15);
      #pragma unroll
      for (int q=0;q<4;q++) O0s[(t+q)*128 + j] = f2bf(acc[q]);
    }
    __syncthreads();
    ushort* BCs = (ushort*)Af;
    #pragma unroll
    for (int jt=0; jt<8; ++jt) {
      f32x4 acc = tile64(KTD, r0, Ut, jt*16, lane);
      int i = r0 + orow;
      int j = jt*16 + (lane&15);
      #pragma unroll
      for (int q=0;q<4;q++) BCs[(i+q)*128 + j] = f2bf(acc[q]);
    }
    __syncthreads();
    #pragma unroll
    for (int idx = tid; idx < 1024; idx += 256) {
      int row = idx >> 4, seg = idx & 15;
      *(uint4*)&o0b[((l0 + row)*HE_ + he)*DV_ + seg*8] = *(const uint4*)&O0s[row*128 + seg*8];
      *(uint4*)&Bcb[bb + (size_t)row*128 + seg*8]      = *(const uint4*)&BCs[row*128 + seg*8];
    }
  }
}

// ---------------- stage one 4096-bf16 chunk (Qt or Mc) into LDS (256 thr) ----------------
__device__ __forceinline__ void stage_qm(const ushort* __restrict__ src, ushort* dst,
                                         int wave, int lane)
{
  #pragma unroll
  for (int pass = 0; pass < 2; ++pass){
    int idx = pass*256 + wave*64 + lane;   // 0..511, 16B each
    __builtin_amdgcn_global_load_lds(
      (const __attribute__((address_space(1))) void*)(src + (size_t)idx*8),
      (__attribute__((address_space(3))) void*)(dst + (size_t)idx*8), 16, 0, 0);
  }
}

// ---------------- fused pass B+C: sequential compose + correction (write-only) -----
// grid (32 s, 16 slices of 8 cols), 256-thr blocks (4 thr/row, 2 cols each)
// -> 512 blocks = 2 chains/CU; id%8 = s%8 = b*4+h -> same XCD as producer.
// Proven shape (rounds 11/12/15): per-instruction-uniform gb + quad broadcast
// -> conflict-free; 2 cols/thread amortizes the bf16 unpack (round-16 lesson:
// 1 col/thread doubles GPU-total unpack -> VALU-bound).
__global__ __launch_bounds__(256) void compose_correct(
    const ushort* __restrict__ Mcb, const ushort* __restrict__ Bcb,
    const ushort* __restrict__ Qtb, ushort* __restrict__ o_corrb)
{
  __shared__ ushort Ql[2][4096];  // staged Qt chunk [t][64] swizzled
  __shared__ ushort Ml[2][4096];  // staged MT chunk [i][64] swizzled
  __shared__ float SSl[512];      // running state slice [64][8]
  const int s   = blockIdx.x;
  const int h   = s & 3;
  const int b   = (s >> 2) & 1;
  const int r   = s >> 3;
  const int he  = h*4 + r;
  const int bhe = b*HE_ + he;
  const int j0  = blockIdx.y * 8;
  const int tid = threadIdx.x;
  const int wave = tid >> 6, lane = tid & 63;
  const int rw = tid >> 2;        // row 0..63
  const int jg = tid & 3;         // col pair within slice (2 cols each)
  const int rsw = rw & 7;         // read-side granule swizzle

  for (int idx = tid; idx < 512; idx += 256) SSl[idx] = 0.f;

  stage_qm(Mcb + (size_t)(bhe*NC_)*4096, Ml[0], wave, lane);
  float2 bcur;
  {
    uint32_t bw = *(const uint32_t*)&Bcb[(size_t)(bhe*NC_)*8192 + rw*128 + j0 + jg*2];
    bcur = make_float2(bf2f((ushort)(bw&0xffff)), bf2f((ushort)(bw>>16)));
  }
  __syncthreads();

  int p = 0;
  for (int c = 0; c < NC_; ++c){
    float2 bnext = make_float2(0.f,0.f);
    if (c+1 < NC_){
      stage_qm(Qtb + (size_t)(bhe*NC_ + c + 1)*4096, Ql[p^1], wave, lane);
      if (c+1 < NC_-1){
        stage_qm(Mcb + (size_t)(bhe*NC_ + c + 1)*4096, Ml[p^1], wave, lane);
        uint32_t bw = *(const uint32_t*)&Bcb[(size_t)(bhe*NC_ + c + 1)*8192 + rw*128 + j0 + jg*2];
        bnext = make_float2(bf2f((ushort)(bw&0xffff)), bf2f((ushort)(bw>>16)));
      }
    }
    const float2* SS2 = (const float2*)SSl;
    float2 oa = make_float2(0.f,0.f);
    if (c > 0){
      const ushort* Qr = Ql[p] + rw*64;
      #pragma unroll
      for (int gb = 0; gb < 8; ++gb){
        uint4 w = *(const uint4*)&Qr[(gb ^ rsw) << 3];
        float f[8]; unpk8(w, f);
        #pragma unroll
        for (int e = 0; e < 8; ++e){
          float2 sv = SS2[(gb*8+e)*4 + jg];
          oa.x += f[e]*sv.x; oa.y += f[e]*sv.y;
        }
      }
    }
    {
      size_t oi = (((size_t)b*L_ + c*T_ + rw)*HE_ + he)*DV_ + j0 + jg*2;
      *(uint32_t*)&o_corrb[oi] = pk2(oa.x, oa.y);
    }
    float2 ns = bcur;
    if (c < NC_-1){
      const ushort* Mr = Ml[p] + rw*64;
      #pragma unroll
      for (int gb = 0; gb < 8; ++gb){
        uint4 w = *(const uint4*)&Mr[(gb ^ rsw) << 3];
        float f[8]; unpk8(w, f);
        #pragma unroll
        for (int e = 0; e < 8; ++e){
          float2 sv = SS2[(gb*8+e)*4 + jg];
          ns.x += f[e]*sv.x; ns.y += f[e]*sv.y;
        }
      }
    }
    __syncthreads();
    if (c < NC_-1) *(float2*)&SSl[rw*8 + jg*2] = ns;
    __syncthreads();
    p ^= 1;
    bcur = bnext;
  }
}

// ---------------- expert combine + RMSNorm*SiLU(gate) -> bf16 ----------------
__global__ __launch_bounds__(128) void combine(const ushort* __restrict__ o0b,
    const ushort* __restrict__ o_corrb, const float* __restrict__ w_buf,
    const ushort* __restrict__ kvgba_b, const float* __restrict__ norm_w,
    ushort* __restrict__ o_fin)
{
  int n  = blockIdx.x;
  int h  = n & 3;
  int bl = n >> 2;
  int j  = threadIdx.x;
  size_t wb = (size_t)bl*16 + h*4;
  size_t ob = wb*128 + j;
  float oc = 0.f;
  #pragma unroll
  for (int r = 0; r < 4; r++){
    size_t oi = ob + (size_t)r*128;
    oc += w_buf[wb+r] * (bf2f(o0b[oi]) + bf2f(o_corrb[oi]));
  }
  float ss = oc*oc;
  #pragma unroll
  for (int off = 32; off > 0; off >>= 1) ss += __shfl_xor(ss, off);
  __shared__ float red[2];
  if ((threadIdx.x & 63) == 0) red[threadIdx.x >> 6] = ss;
  __syncthreads();
  float mean = (red[0] + red[1]) * (1.f/128.f);
  float sc = rsqrtf(mean + 1e-5f);
  float gv = bf2f(kvgba_b[(size_t)bl*NCAT + 768 + h*128 + j]);
  o_fin[(size_t)bl*512 + h*128 + j] = f2bf(oc * sc * norm_w[j] * (gv * sigmoidf_(gv)));
}

extern "C" void kernel_launch(void* const* d_in, const int* in_sizes, int n_in,
                              void* d_out, int out_size, void* d_ws, size_t ws_size,
                              hipStream_t stream)
{
  (void)in_sizes; (void)n_in; (void)out_size; (void)ws_size;
  const float* x       = (const float*)d_in[0];
  const float* Wq      = (const float*)d_in[1];
  const float* Wk      = (const float*)d_in[2];
  const float* Wv      = (const float*)d_in[3];
  const float* Wb      = (const float*)d_in[4];
  const float* Wa      = (const float*)d_in[5];
  const float* Wg      = (const float*)d_in[6];
  const float* Wo      = (const float*)d_in[7];
  const float* conv_q  = (const float*)d_in[8];
  const float* conv_k  = (const float*)d_in[9];
  const float* conv_v  = (const float*)d_in[10];
  const float* Wq_exp  = (const float*)d_in[11];
  const float* Wk_exp  = (const float*)d_in[12];
  const float* W_gate  = (const float*)d_in[13];
  const float* A_log   = (const float*)d_in[14];
  const float* dt_bias = (const float*)d_in[15];
  const float* norm_w  = (const float*)d_in[16];
  float* out = (float*)d_out;

  const size_t BL = (size_t)B_*L_;   // 4096
  float* p = (float*)d_ws;
  float* q_lin  = p; p += BL*256;
  float* q_conv = p; p += BL*256;
  float* w_buf  = p; p += BL*16;
  float* bt_T   = p; p += BL*16;   // [16][4096]
  float* g_T    = p; p += BL*16;   // [16][4096]
  ushort* kvgba_b=(ushort*)p; p += BL*NCAT/2;  // bf16 [bl][1408]
  ushort* o0b   = (ushort*)p; p += BL*16*64;   // bf16 [bl][16][128]
  ushort* o_corrb=(ushort*)p; p += BL*16*64;   // bf16 [bl][16][128]
  ushort* Mcb   = (ushort*)p; p += (size_t)B_*HE_*NC_*2048;  // bf16 [chunk][64][64]
  ushort* Qtb   = (ushort*)p; p += (size_t)B_*HE_*NC_*2048;
  ushort* Bcb   = (ushort*)p; p += (size_t)B_*HE_*NC_*4096;  // bf16 [chunk][64][128]
  ushort* v_convb=(ushort*)p; p += BL*256;        // v bf16 [bl][512]
  ushort* xb    = (ushort*)p; p += BL*512;        // x bf16
  ushort* Wcat  = (ushort*)p; p += (NCAT*1024)/2; // concat weights bf16
  ushort* qc_bf = (ushort*)p; p += BL*128;        // q_conv bf16
  ushort* kc_bf = (ushort*)p; p += BL*128;        // k_conv bf16
  ushort* qeb   = (ushort*)p; p += BL*512;        // qe bf16 [4096][1024]
  ushort* keb   = (ushort*)p; p += BL*512;        // ke bf16
  ushort* Wqeb  = (ushort*)p; p += 32768;
  ushort* Wkeb  = (ushort*)p; p += 32768;
  ushort* Wob   = (ushort*)p; p += 262144;        // 1024*512 bf16
  ushort* o_finb= (ushort*)p; p += BL*256;        // bf16 [4096][512]

  // weight prep
  concat_wcat<<<dim3((NCAT*1024+255)/256), dim3(256), 0, stream>>>(Wk, Wv, Wg, Wb, Wa, Wcat);
  { int n = (int)(BL*1024); cast_bf16<<<dim3((n+255)/256), dim3(256), 0, stream>>>(x, xb, n); }
  cast3<<<dim3((655360+255)/256), dim3(256), 0, stream>>>(Wq_exp, Wk_exp, Wo, Wqeb, Wkeb, Wob);

  // projections (kvgba bf16 out)
  gemm_f32_db<<<dim3(4, 64), dim3(256), 0, stream>>>(x, 1024, Wq, 1024, q_lin, 256, 4096, 256, 1024);
  gemm_bf16_bfout<<<dim3(NCAT/128, 32), dim3(256), 0, stream>>>(xb, 1024, Wcat, 1024, kvgba_b, NCAT, 1024);

  // fused convs (+SiLU): q|k|v in one launch
  conv_silu_all<<<dim3((int)(BL*1024/256)), dim3(256), 0, stream>>>(
      q_lin, kvgba_b, conv_q, conv_k, conv_v, q_conv, qc_bf, kc_bf, v_convb);

  routing<<<dim3(64), dim3(256), 0, stream>>>(q_conv, kvgba_b, W_gate, A_log, dt_bias,
                                              w_buf, bt_T, g_T);

  gemm_expand_bf16<<<dim3(2, 32, 8), dim3(256), 0, stream>>>(qc_bf, kc_bf, Wqeb, Wkeb, qeb, keb);

  // scan (fused l2norm): id = c*32 + s, s = r*8 + b*4 + h
  scan_chunk_mfma<<<dim3(NC_*HE_*B_), dim3(256), 0, stream>>>(keb, qeb, v_convb, bt_T, g_T,
                                                              o0b, Qtb, Mcb, Bcb);
  compose_correct<<<dim3(32, 16), dim3(256), 0, stream>>>(Mcb, Bcb, Qtb, o_corrb);
  combine<<<dim3(B_*L_*H_), dim3(128), 0, stream>>>(o0b, o_corrb, w_buf, kvgba_b, norm_w, o_finb);

  gemm_bf16<<<dim3(8, 32), dim3(256), 0, stream>>>(o_finb, 512, Wob, 512, out, 1024, 512);
}